// Round 14
// baseline (7336.038 us; speedup 1.0000x reference)
//
#include <hip/hip_runtime.h>
#include <hip/hip_bf16.h>

// GRU: B=64, S=512, I=1024, H=1024, fp32 in/out, final h only.
// Round 14: independent per-wave chains. 64 WGs x 4 waves; wave (Q,g) owns
// batch-group g x units [16Q,16Q+16) x full K=1024. No intra-WG sync in the
// loop. ALL global ordering is compiler-managed: h exchange via __hip_atomic
// loads/stores (AGENT), flag signal via RELEASE store (emits the per-wave
// vmcnt(0) drain = r12's invariant by construction), poll via ACQUIRE.
// No inline-asm VMEM anywhere. W_hh in LDS (compiler lgkmcnt). hbuf in the
// r2 fragment layout for coalesced A-fragment loads.

#define B_ 64
#define S_ 512
#define H_ 1024

typedef __bf16 bf16;
typedef __bf16 bf16x8 __attribute__((ext_vector_type(8)));
typedef float  f32x4  __attribute__((ext_vector_type(4)));
typedef unsigned int u32;
typedef unsigned long long u64;

union Frag { u64 q[2]; bf16x8 v; };

// ---------------- init: zero flags, pack h0 (fragment layout) ---------------
__global__ void k_init(const float* __restrict__ h0, bf16* __restrict__ hbuf,
                       u32* __restrict__ flags) {
  int t = blockIdx.x * 256 + threadIdx.x;
  if (t < 4096) flags[t] = 0u;
  if (t < B_ * H_) {
    int b = t >> 10, j = t & 1023;
    hbuf[((size_t)((j >> 3) * 64 + b)) * 8 + (j & 7)] = (bf16)h0[t];
  }
}

// ---------------- gi GEMM: [32768,1024] x [1024,3072] -> bf16 ---------------
__global__ __launch_bounds__(256) void k_gemm(const float* __restrict__ X,
                                              const float* __restrict__ W,
                                              const float* __restrict__ bias,
                                              bf16* __restrict__ gi) {
  __shared__ bf16 As[128 * 40];
  __shared__ bf16 Bs[128 * 40];
  const int tid = threadIdx.x;
  const int bidn = blockIdx.x % 24, bidm = blockIdx.x / 24;
  const int row = tid >> 1, half = tid & 1;
  const float* ax = X + (size_t)(bidm * 128 + row) * 1024 + half * 16;
  const float* bw = W + (size_t)(bidn * 128 + row) * 1024 + half * 16;
  const int lane = tid & 63, wave = tid >> 6;
  const int wm = wave >> 1, wn = wave & 1;

  f32x4 acc[4][4];
#pragma unroll
  for (int i = 0; i < 4; ++i)
#pragma unroll
    for (int j = 0; j < 4; ++j) acc[i][j] = (f32x4){0.f, 0.f, 0.f, 0.f};

  for (int ks = 0; ks < 32; ++ks) {
    {
      const float* pa = ax + ks * 32;
      f32x4 a0 = *(const f32x4*)(pa);
      f32x4 a1 = *(const f32x4*)(pa + 4);
      f32x4 a2 = *(const f32x4*)(pa + 8);
      f32x4 a3 = *(const f32x4*)(pa + 12);
      bf16x8 v0, v1;
#pragma unroll
      for (int i = 0; i < 4; ++i) {
        v0[i] = (bf16)a0[i]; v0[4 + i] = (bf16)a1[i];
        v1[i] = (bf16)a2[i]; v1[4 + i] = (bf16)a3[i];
      }
      *(bf16x8*)&As[row * 40 + half * 16]     = v0;
      *(bf16x8*)&As[row * 40 + half * 16 + 8] = v1;

      const float* pb = bw + ks * 32;
      f32x4 b0 = *(const f32x4*)(pb);
      f32x4 b1 = *(const f32x4*)(pb + 4);
      f32x4 b2 = *(const f32x4*)(pb + 8);
      f32x4 b3 = *(const f32x4*)(pb + 12);
#pragma unroll
      for (int i = 0; i < 4; ++i) {
        v0[i] = (bf16)b0[i]; v0[4 + i] = (bf16)b1[i];
        v1[i] = (bf16)b2[i]; v1[4 + i] = (bf16)b3[i];
      }
      *(bf16x8*)&Bs[row * 40 + half * 16]     = v0;
      *(bf16x8*)&Bs[row * 40 + half * 16 + 8] = v1;
    }
    __syncthreads();
    bf16x8 af[4], bfr[4];
#pragma unroll
    for (int mi = 0; mi < 4; ++mi)
      af[mi] = *(const bf16x8*)&As[(wm * 64 + mi * 16 + (lane & 15)) * 40 + (lane >> 4) * 8];
#pragma unroll
    for (int ni = 0; ni < 4; ++ni)
      bfr[ni] = *(const bf16x8*)&Bs[(wn * 64 + ni * 16 + (lane & 15)) * 40 + (lane >> 4) * 8];
#pragma unroll
    for (int mi = 0; mi < 4; ++mi)
#pragma unroll
      for (int ni = 0; ni < 4; ++ni)
        acc[mi][ni] = __builtin_amdgcn_mfma_f32_16x16x32_bf16(af[mi], bfr[ni], acc[mi][ni], 0, 0, 0);
    __syncthreads();
  }

  float bv[4];
#pragma unroll
  for (int ni = 0; ni < 4; ++ni)
    bv[ni] = bias[bidn * 128 + wn * 64 + ni * 16 + (lane & 15)];
#pragma unroll
  for (int mi = 0; mi < 4; ++mi)
#pragma unroll
    for (int ni = 0; ni < 4; ++ni)
#pragma unroll
      for (int r = 0; r < 4; ++r) {
        int grow = bidm * 128 + wm * 64 + mi * 16 + (lane >> 4) * 4 + r;
        int gcol = bidn * 128 + wn * 64 + ni * 16 + (lane & 15);
        gi[(size_t)grow * 3072 + gcol] = (bf16)(acc[mi][ni][r] + bv[ni]);
      }
}

// ---------------- persistent recurrent kernel: per-wave chains --------------
// Per t per wave: [poll 64 flags ACQUIRE] -> 32 A-fragments (2x16 windows,
// RELAXED atomic u64 loads, compiler-tracked) -> 96 MFMA vs LDS W -> gates
// in-register -> pair-packed u32 atomic h-stores -> lane0 RELEASE flag store
// (compiler emits the per-wave vmcnt(0) drain before it).
__global__ __launch_bounds__(256, 1) void k_rnn(
    const float* __restrict__ h0, const float* __restrict__ Whh,
    const float* __restrict__ bhh, const bf16* __restrict__ gi,
    bf16* __restrict__ hbuf, float* __restrict__ out, u32* __restrict__ flags) {
  __shared__ bf16 wlds[128 * 49 * 8];   // [(k8*49 + gate*16+u)*8] fragments

  const int tid = threadIdx.x;
  const int Q = blockIdx.x;              // unit block (16 units)
  const int g = tid >> 6;                // wave = batch group
  const int lane = tid & 63;
  const int un = lane & 15, kq = lane >> 4;
  const int jj = Q * 16 + un;            // this lane's unit (B/C col role)
  const int bb0 = g * 16 + kq * 4;       // this lane's batches (C row role)

  for (int idx = tid; idx < 48 * 128; idx += 256) {
    int c = idx % 48, k8 = idx / 48;
    int ga = c >> 4, ur = c & 15;
    const float* src = Whh + (size_t)(ga * 1024 + Q * 16 + ur) * 1024 + k8 * 8;
    bf16x8 v;
#pragma unroll
    for (int e = 0; e < 8; ++e) v[e] = (bf16)src[e];
    *(bf16x8*)&wlds[(size_t)(k8 * 49 + c) * 8] = v;
  }
  __syncthreads();   // only barrier; waves free-run afterwards

  float hold[4];
#pragma unroll
  for (int r = 0; r < 4; ++r) hold[r] = h0[(size_t)(bb0 + r) * 1024 + jj];
  const float bh0 = bhh[jj], bh1 = bhh[1024 + jj], bh2 = bhh[2048 + jj];

  int bad = 0;
  for (int t = 0; t < 512; ++t) {
    const bf16* cur = hbuf + (size_t)(t & 1) * 65536;
    bf16* nxt = hbuf + (size_t)((t + 1) & 1) * 65536;

    // gi for this step (plain loads — gi is pre-kernel data, no flags needed)
    float gc[4][3];
#pragma unroll
    for (int r = 0; r < 4; ++r) {
      const bf16* p = gi + ((size_t)(bb0 + r) * 512 + t) * 3072 + jj;
      gc[r][0] = (float)p[0];
      gc[r][1] = (float)p[1024];
      gc[r][2] = (float)p[2048];
    }

    if (t > 0 && !bad) {
      // lane i watches producer WG i's flag for this group; ACQUIRE orders
      // the subsequent aff loads after the observed flag.
      int guard = 0;
      while (1) {
        u32 f = __hip_atomic_load(&flags[g * 64 + lane], __ATOMIC_ACQUIRE,
                                  __HIP_MEMORY_SCOPE_AGENT);
        if (__all(f >= (u32)t)) break;
        if (++guard > (1 << 14)) { bad = 1; break; }
        __builtin_amdgcn_s_sleep(1);
      }
    }

    // A-fragments: fragment kk at u64 index kk*512 + kq*128 + 2*(g*16+un)
    const u64* ap = (const u64*)cur + (size_t)kq * 128 + 2 * (g * 16 + un);
    f32x4 a0 = (f32x4){0.f, 0.f, 0.f, 0.f};
    f32x4 a1 = (f32x4){0.f, 0.f, 0.f, 0.f};
    f32x4 a2 = (f32x4){0.f, 0.f, 0.f, 0.f};
    Frag aw[16];
#pragma unroll
    for (int kk = 0; kk < 16; ++kk) {
      aw[kk].q[0] = __hip_atomic_load(ap + (size_t)kk * 512,
                                      __ATOMIC_RELAXED, __HIP_MEMORY_SCOPE_AGENT);
      aw[kk].q[1] = __hip_atomic_load(ap + (size_t)kk * 512 + 1,
                                      __ATOMIC_RELAXED, __HIP_MEMORY_SCOPE_AGENT);
    }
#pragma unroll
    for (int kk = 0; kk < 16; ++kk) {
      const bf16* wb = &wlds[(size_t)((kk * 4 + kq) * 49 + un) * 8];
      a0 = __builtin_amdgcn_mfma_f32_16x16x32_bf16(aw[kk].v, *(const bf16x8*)(wb), a0, 0, 0, 0);
      a1 = __builtin_amdgcn_mfma_f32_16x16x32_bf16(aw[kk].v, *(const bf16x8*)(wb + 128), a1, 0, 0, 0);
      a2 = __builtin_amdgcn_mfma_f32_16x16x32_bf16(aw[kk].v, *(const bf16x8*)(wb + 256), a2, 0, 0, 0);
    }
#pragma unroll
    for (int kk = 0; kk < 16; ++kk) {
      aw[kk].q[0] = __hip_atomic_load(ap + (size_t)(kk + 16) * 512,
                                      __ATOMIC_RELAXED, __HIP_MEMORY_SCOPE_AGENT);
      aw[kk].q[1] = __hip_atomic_load(ap + (size_t)(kk + 16) * 512 + 1,
                                      __ATOMIC_RELAXED, __HIP_MEMORY_SCOPE_AGENT);
    }
#pragma unroll
    for (int kk = 0; kk < 16; ++kk) {
      const bf16* wb = &wlds[(size_t)(((kk + 16) * 4 + kq) * 49 + un) * 8];
      a0 = __builtin_amdgcn_mfma_f32_16x16x32_bf16(aw[kk].v, *(const bf16x8*)(wb), a0, 0, 0, 0);
      a1 = __builtin_amdgcn_mfma_f32_16x16x32_bf16(aw[kk].v, *(const bf16x8*)(wb + 128), a1, 0, 0, 0);
      a2 = __builtin_amdgcn_mfma_f32_16x16x32_bf16(aw[kk].v, *(const bf16x8*)(wb + 256), a2, 0, 0, 0);
    }

    float hn[4];
#pragma unroll
    for (int r = 0; r < 4; ++r) {
      float rg = 1.f / (1.f + __expf(-(gc[r][0] + a0[r] + bh0)));
      float zg = 1.f / (1.f + __expf(-(gc[r][1] + a1[r] + bh1)));
      float e2 = __expf(2.f * (gc[r][2] + rg * (a2[r] + bh2)));
      float tng = 1.f - 2.f / (e2 + 1.f);
      hn[r] = (1.f - zg) * tng + zg * hold[r];
      hold[r] = hn[r];
    }

    if (t < 511) {
      // pair-pack bf16 across (even,odd) unit lanes -> one u32 atomic store.
      // Fragment layout: element (b,j) at ((j>>3)*64+b)*8+(j&7); units jj and
      // jj+1 (un even) are adjacent elements -> one aligned u32.
#pragma unroll
      for (int r = 0; r < 4; ++r) {
        unsigned short hb = __builtin_bit_cast(unsigned short, (bf16)hn[r]);
        int ob = __shfl_xor((int)hb, 1, 64);
        if (!(un & 1)) {
          u32 word = (u32)hb | ((u32)(unsigned short)ob << 16);
          size_t eoff = ((size_t)(jj >> 3) * 64 + (bb0 + r)) * 8 + ((un & 7) & ~1);
          __hip_atomic_store((u32*)(nxt + eoff), word,
                             __ATOMIC_RELAXED, __HIP_MEMORY_SCOPE_AGENT);
        }
      }
      // RELEASE: compiler emits the per-wave vmcnt(0) drain before this store
      // -> all 64 lanes' h-stores are globally visible before the flag.
      if (lane == 0)
        __hip_atomic_store(&flags[g * 64 + Q], (u32)(t + 1),
                           __ATOMIC_RELEASE, __HIP_MEMORY_SCOPE_AGENT);
    } else {
#pragma unroll
      for (int r = 0; r < 4; ++r)
        out[(size_t)(bb0 + r) * 1024 + jj] = bad ? 12345.0f : hn[r];
    }
  }
}

__global__ void k_fail(float* out, float v) {
  if (threadIdx.x == 0 && blockIdx.x == 0) out[0] = v;
}

extern "C" void kernel_launch(void* const* d_in, const int* in_sizes, int n_in,
                              void* d_out, int out_size, void* d_ws, size_t ws_size,
                              hipStream_t stream) {
  const float* x   = (const float*)d_in[0];
  const float* h0  = (const float*)d_in[1];
  const float* Wih = (const float*)d_in[2];
  const float* Whh = (const float*)d_in[3];
  const float* bih = (const float*)d_in[4];
  const float* bhh = (const float*)d_in[5];
  float* out = (float*)d_out;

  const size_t GI_BYTES  = (size_t)32768 * 3072 * 2;  // 201,326,592
  const size_t HB_BYTES  = (size_t)2 * 65536 * 2;     // 262,144
  const size_t BAR_BYTES = 4096 * 4;                  // 16,384
  if (ws_size < GI_BYTES + HB_BYTES + BAR_BYTES) {
    k_fail<<<1, 64, 0, stream>>>(out, (float)ws_size);
    return;
  }
  char* ws = (char*)d_ws;
  bf16* gi = (bf16*)ws;
  bf16* hbuf = (bf16*)(ws + GI_BYTES);
  u32* flags = (u32*)(ws + GI_BYTES + HB_BYTES);

  k_init<<<256, 256, 0, stream>>>(h0, hbuf, flags);
  k_gemm<<<6144, 256, 0, stream>>>(x, Wih, bih, gi);
  k_rnn<<<64, 256, 0, stream>>>(h0, Whh, bhh, gi, hbuf, out, flags);
}

// Round 15
// 2969.244 us; speedup vs baseline: 2.4707x; 2.4707x over previous
//
#include <hip/hip_runtime.h>
#include <hip/hip_bf16.h>

// GRU: B=64, S=512, I=1024, H=1024, fp32 in/out, final h only.
// Round 15 = r13's proven discipline with 2 groups per phase (2 phases/t,
// half the sync tax). Invariants kept: per-wave vmcnt(0) BEFORE sync#1;
// uniform gate vmcnt(6); signal only after a dedicated store-only vmcnt(0);
// preload drained pre-sync + laundered; fallback poll; W_hh in registers.

#define B_ 64
#define S_ 512
#define H_ 1024

typedef __bf16 bf16;
typedef __bf16 bf16x8 __attribute__((ext_vector_type(8)));
typedef float  f32x4  __attribute__((ext_vector_type(4)));
typedef unsigned int u32;

__device__ __forceinline__ void ld_cc16(const bf16* p, f32x4* dst) {
  asm volatile("global_load_dwordx4 %0, %1, off sc0 sc1" : "=v"(*dst) : "v"(p));
}
__device__ __forceinline__ void ld_u16(const bf16* p, u32* dst) {
  asm volatile("global_load_ushort %0, %1, off" : "=v"(*dst) : "v"(p));
}
__device__ __forceinline__ void st_cc16(bf16* p, u32 bits) {
  asm volatile("global_store_short %0, %1, off sc0 sc1" :: "v"(p), "v"(bits) : "memory");
}
#define WAITV(N) \
  asm volatile("s_waitcnt vmcnt(" #N ")" ::: "memory"); \
  __builtin_amdgcn_sched_barrier(0)

// ---------------- init: zero flags, pack h0 into hbuf[0] --------------------
__global__ void k_init(const float* __restrict__ h0, bf16* __restrict__ hbuf,
                       u32* __restrict__ flags) {
  int t = blockIdx.x * 256 + threadIdx.x;
  if (t < 4096) flags[t] = 0u;
  if (t < B_ * H_) {
    int b = t >> 10, j = t & 1023;
    hbuf[((size_t)((j >> 3) * 64 + b)) * 8 + (j & 7)] = (bf16)h0[t];
  }
}

// ---------------- gi GEMM: [32768,1024] x [1024,3072] -> bf16 ---------------
__global__ __launch_bounds__(256) void k_gemm(const float* __restrict__ X,
                                              const float* __restrict__ W,
                                              const float* __restrict__ bias,
                                              bf16* __restrict__ gi) {
  __shared__ bf16 As[128 * 40];
  __shared__ bf16 Bs[128 * 40];
  const int tid = threadIdx.x;
  const int bidn = blockIdx.x % 24, bidm = blockIdx.x / 24;
  const int row = tid >> 1, half = tid & 1;
  const float* ax = X + (size_t)(bidm * 128 + row) * 1024 + half * 16;
  const float* bw = W + (size_t)(bidn * 128 + row) * 1024 + half * 16;
  const int lane = tid & 63, wave = tid >> 6;
  const int wm = wave >> 1, wn = wave & 1;

  f32x4 acc[4][4];
#pragma unroll
  for (int i = 0; i < 4; ++i)
#pragma unroll
    for (int j = 0; j < 4; ++j) acc[i][j] = (f32x4){0.f, 0.f, 0.f, 0.f};

  for (int ks = 0; ks < 32; ++ks) {
    {
      const float* pa = ax + ks * 32;
      f32x4 a0 = *(const f32x4*)(pa);
      f32x4 a1 = *(const f32x4*)(pa + 4);
      f32x4 a2 = *(const f32x4*)(pa + 8);
      f32x4 a3 = *(const f32x4*)(pa + 12);
      bf16x8 v0, v1;
#pragma unroll
      for (int i = 0; i < 4; ++i) {
        v0[i] = (bf16)a0[i]; v0[4 + i] = (bf16)a1[i];
        v1[i] = (bf16)a2[i]; v1[4 + i] = (bf16)a3[i];
      }
      *(bf16x8*)&As[row * 40 + half * 16]     = v0;
      *(bf16x8*)&As[row * 40 + half * 16 + 8] = v1;

      const float* pb = bw + ks * 32;
      f32x4 b0 = *(const f32x4*)(pb);
      f32x4 b1 = *(const f32x4*)(pb + 4);
      f32x4 b2 = *(const f32x4*)(pb + 8);
      f32x4 b3 = *(const f32x4*)(pb + 12);
#pragma unroll
      for (int i = 0; i < 4; ++i) {
        v0[i] = (bf16)b0[i]; v0[4 + i] = (bf16)b1[i];
        v1[i] = (bf16)b2[i]; v1[4 + i] = (bf16)b3[i];
      }
      *(bf16x8*)&Bs[row * 40 + half * 16]     = v0;
      *(bf16x8*)&Bs[row * 40 + half * 16 + 8] = v1;
    }
    __syncthreads();
    bf16x8 af[4], bfr[4];
#pragma unroll
    for (int mi = 0; mi < 4; ++mi)
      af[mi] = *(const bf16x8*)&As[(wm * 64 + mi * 16 + (lane & 15)) * 40 + (lane >> 4) * 8];
#pragma unroll
    for (int ni = 0; ni < 4; ++ni)
      bfr[ni] = *(const bf16x8*)&Bs[(wn * 64 + ni * 16 + (lane & 15)) * 40 + (lane >> 4) * 8];
#pragma unroll
    for (int mi = 0; mi < 4; ++mi)
#pragma unroll
      for (int ni = 0; ni < 4; ++ni)
        acc[mi][ni] = __builtin_amdgcn_mfma_f32_16x16x32_bf16(af[mi], bfr[ni], acc[mi][ni], 0, 0, 0);
    __syncthreads();
  }

  float bv[4];
#pragma unroll
  for (int ni = 0; ni < 4; ++ni)
    bv[ni] = bias[bidn * 128 + wn * 64 + ni * 16 + (lane & 15)];
#pragma unroll
  for (int mi = 0; mi < 4; ++mi)
#pragma unroll
    for (int ni = 0; ni < 4; ++ni)
#pragma unroll
      for (int r = 0; r < 4; ++r) {
        int grow = bidm * 128 + wm * 64 + mi * 16 + (lane >> 4) * 4 + r;
        int gcol = bidn * 128 + wn * 64 + ni * 16 + (lane & 15);
        gi[(size_t)grow * 3072 + gcol] = (bf16)(acc[mi][ni][r] + bv[ni]);
      }
}

// ---------------- persistent recurrent kernel: 2 phases per t ---------------
// Phase(t,P) handles groups GA=2P, GB=2P+1 (reads h_t, writes h_{t+1}).
// Body: gate vmcnt(6) [aff16 ready; queue=[sig<=1,aff16,gi6]]
//   -> issue flag preload for the NEXT phase's data -> 48 MFMA -> plds
//   -> per-wave vmcnt(0) -> sync#1 -> launder+check (fallback poll)
//   -> s_barrier#2 -> gates(2 groups) -> h-stores -> vmcnt(0) [stores only]
//   -> signal flags[GA],[GB]=t+1 (tid0/tid64) -> refill aff+gi (next phase)
//   -> s_barrier#3.
#define PHASE2(P, HA, HB) {                                                   \
  if (t == 0 && (P) == 0) { WAITV(0); } else { WAITV(6); }                    \
  const int cga = (P) == 0 ? 2 : 0;                                           \
  const u32 tn  = (P) == 0 ? (u32)t : (u32)(t + 1);                           \
  const bool do_chk = ((P) == 0) ? (t > 0) : (t < 511);                       \
  u32 fpre = 0xFFFFFFFFu;                                                     \
  if (do_chk) {                                                               \
    const u32* fp = flags + ((cga + (wave & 1)) * 64 + lane) * 16;            \
    asm volatile("global_load_dword %0, %1, off sc0 sc1"                      \
                 : "=v"(fpre) : "v"(fp));                                     \
  }                                                                           \
  f32x4 aA0 = (f32x4){0.f,0.f,0.f,0.f}, aA1 = aA0, aA2 = aA0;                 \
  f32x4 aB0 = aA0, aB1 = aA0, aB2 = aA0;                                      \
  _Pragma("unroll")                                                           \
  for (int kk = 0; kk < 8; ++kk) {                                            \
    bf16x8 a = __builtin_bit_cast(bf16x8, affA[kk]);                          \
    aA0 = __builtin_amdgcn_mfma_f32_16x16x32_bf16(a, wreg[kk*3+0], aA0, 0,0,0);\
    aA1 = __builtin_amdgcn_mfma_f32_16x16x32_bf16(a, wreg[kk*3+1], aA1, 0,0,0);\
    aA2 = __builtin_amdgcn_mfma_f32_16x16x32_bf16(a, wreg[kk*3+2], aA2, 0,0,0);\
  }                                                                           \
  _Pragma("unroll")                                                           \
  for (int kk = 0; kk < 8; ++kk) {                                            \
    bf16x8 a = __builtin_bit_cast(bf16x8, affB[kk]);                          \
    aB0 = __builtin_amdgcn_mfma_f32_16x16x32_bf16(a, wreg[kk*3+0], aB0, 0,0,0);\
    aB1 = __builtin_amdgcn_mfma_f32_16x16x32_bf16(a, wreg[kk*3+1], aB1, 0,0,0);\
    aB2 = __builtin_amdgcn_mfma_f32_16x16x32_bf16(a, wreg[kk*3+2], aB2, 0,0,0);\
  }                                                                           \
  {                                                                           \
    int prow = wave * 16 + kq * 4;                                            \
    _Pragma("unroll")                                                         \
    for (int r = 0; r < 4; ++r) {                                             \
      plds[(prow + r) * 48 + un]            = aA0[r];                         \
      plds[(prow + r) * 48 + 16 + un]       = aA1[r];                         \
      plds[(prow + r) * 48 + 32 + un]       = aA2[r];                         \
      plds[3072 + (prow + r) * 48 + un]      = aB0[r];                        \
      plds[3072 + (prow + r) * 48 + 16 + un] = aB1[r];                        \
      plds[3072 + (prow + r) * 48 + 32 + un] = aB2[r];                        \
    }                                                                         \
  }                                                                           \
  WAITV(0);              /* r12 invariant: all waves drain BEFORE barrier */  \
  __syncthreads();                                                            \
  if (do_chk) {                                                               \
    asm volatile("" : "+v"(fpre));                                            \
    if (!__all(fpre >= tn)) {                                                 \
      const u32* fp = flags + ((cga + (wave & 1)) * 64 + lane) * 16;          \
      int guard = 0;                                                          \
      while (1) {                                                             \
        u32 f = __hip_atomic_load(fp, __ATOMIC_RELAXED,                       \
                                  __HIP_MEMORY_SCOPE_AGENT);                  \
        if (__all(f >= tn)) break;                                            \
        if (++guard > (1 << 16)) { bad = 1; break; }                          \
        __builtin_amdgcn_s_sleep(1);                                          \
      }                                                                       \
    }                                                                         \
  }                                                                           \
  __builtin_amdgcn_s_barrier();   /* #2 */                                    \
  {                                                                           \
    float ghrA = bh0, ghzA = bh1, ghnA = bh2;                                 \
    float ghrB = bh0, ghzB = bh1, ghnB = bh2;                                 \
    _Pragma("unroll")                                                         \
    for (int w = 0; w < 4; ++w) {                                             \
      ghrA += plds[w * 768 + b * 48 + u];                                     \
      ghzA += plds[w * 768 + b * 48 + 16 + u];                                \
      ghnA += plds[w * 768 + b * 48 + 32 + u];                                \
      ghrB += plds[3072 + w * 768 + b * 48 + u];                              \
      ghzB += plds[3072 + w * 768 + b * 48 + 16 + u];                         \
      ghnB += plds[3072 + w * 768 + b * 48 + 32 + u];                         \
    }                                                                         \
    float girA = __builtin_bit_cast(float, gcA0 << 16);                       \
    float gizA = __builtin_bit_cast(float, gcA1 << 16);                       \
    float ginA = __builtin_bit_cast(float, gcA2 << 16);                       \
    float rgA = 1.f / (1.f + __expf(-(girA + ghrA)));                         \
    float zgA = 1.f / (1.f + __expf(-(gizA + ghzA)));                         \
    float e2A = __expf(2.f * (ginA + rgA * ghnA));                            \
    float hnA = (1.f - zgA) * (1.f - 2.f / (e2A + 1.f)) + zgA * HA;           \
    HA = hnA;                                                                 \
    float girB = __builtin_bit_cast(float, gcB0 << 16);                       \
    float gizB = __builtin_bit_cast(float, gcB1 << 16);                       \
    float ginB = __builtin_bit_cast(float, gcB2 << 16);                       \
    float rgB = 1.f / (1.f + __expf(-(girB + ghrB)));                         \
    float zgB = 1.f / (1.f + __expf(-(gizB + ghzB)));                         \
    float e2B = __expf(2.f * (ginB + rgB * ghnB));                            \
    float hnB = (1.f - zgB) * (1.f - 2.f / (e2B + 1.f)) + zgB * HB;           \
    HB = hnB;                                                                 \
    if (t < 511) {                                                            \
      bf16* nxtb = hbuf + (size_t)((t + 1) & 1) * 65536;                      \
      st_cc16(nxtb + hoff0 + (2*(P)) * 128,                                   \
              (u32)__builtin_bit_cast(unsigned short, (bf16)hnA));            \
      st_cc16(nxtb + hoff0 + (2*(P)+1) * 128,                                 \
              (u32)__builtin_bit_cast(unsigned short, (bf16)hnB));            \
      WAITV(0);            /* queue holds ONLY the 2 stores here */           \
      if (tid == 0)                                                           \
        __hip_atomic_store(&flags[((2*(P)) * 64 + Q) * 16], (u32)(t + 1),     \
                           __ATOMIC_RELAXED, __HIP_MEMORY_SCOPE_AGENT);       \
      if (tid == 64)                                                          \
        __hip_atomic_store(&flags[((2*(P)+1) * 64 + Q) * 16], (u32)(t + 1),   \
                           __ATOMIC_RELAXED, __HIP_MEMORY_SCOPE_AGENT);       \
    } else {                                                                  \
      out[(size_t)((2*(P)) * 16 + b) * 1024 + jj]   = bad ? 12345.0f : hnA;   \
      out[(size_t)((2*(P)+1) * 16 + b) * 1024 + jj] = bad ? 12345.0f : hnB;   \
    }                                                                         \
  }                                                                           \
  if (!(t == 511 && (P) == 1)) {                                              \
    const int na = ((P) == 0) ? 2 : 0;                                        \
    const int ntp = ((P) == 0) ? t : t + 1;                                   \
    const bf16* bb = hbuf + (size_t)(ntp & 1) * 65536 + aoff0;                \
    const bf16* abA = bb + na * 128;                                          \
    const bf16* abB = bb + (na + 1) * 128;                                    \
    _Pragma("unroll")                                                         \
    for (int kk = 0; kk < 8; ++kk) ld_cc16(abA + kk * 2048, &affA[kk]);       \
    _Pragma("unroll")                                                         \
    for (int kk = 0; kk < 8; ++kk) ld_cc16(abB + kk * 2048, &affB[kk]);       \
    const bf16* pA = giB + (size_t)na * GSTR + (size_t)ntp * 3072;            \
    const bf16* pB = giB + (size_t)(na + 1) * GSTR + (size_t)ntp * 3072;      \
    ld_u16(pA, &gcA0); ld_u16(pA + 1024, &gcA1); ld_u16(pA + 2048, &gcA2);    \
    ld_u16(pB, &gcB0); ld_u16(pB + 1024, &gcB1); ld_u16(pB + 2048, &gcB2);    \
  }                                                                           \
  __builtin_amdgcn_s_barrier();   /* #3: plds reuse fence */                  \
}

__global__ __launch_bounds__(256, 1) void k_rnn(
    const float* __restrict__ h0, const float* __restrict__ Whh,
    const float* __restrict__ bhh, const bf16* __restrict__ gi,
    bf16* __restrict__ hbuf, float* __restrict__ out, u32* __restrict__ flags) {
  __shared__ bf16 wlds[128 * 49 * 8];   // staging; K-loop never reads it
  __shared__ float plds[2 * 3072];      // 2 group regions, stride 48

  const int tid = threadIdx.x;
  const int Q = blockIdx.x;
  const int lane = tid & 63, wave = tid >> 6;
  const int b = tid >> 4, u = tid & 15;
  const int un = lane & 15, kq = lane >> 4;
  const int jj = Q * 16 + u;

  for (int idx = tid; idx < 48 * 128; idx += 256) {
    int c = idx % 48, k8 = idx / 48;
    int ga = c >> 4, ur = c & 15;
    const float* src = Whh + (size_t)(ga * 1024 + Q * 16 + ur) * 1024 + k8 * 8;
    bf16x8 v;
#pragma unroll
    for (int e = 0; e < 8; ++e) v[e] = (bf16)src[e];
    *(bf16x8*)&wlds[(size_t)(k8 * 49 + c) * 8] = v;
  }
  __syncthreads();

  bf16x8 wreg[24];
#pragma unroll
  for (int kk = 0; kk < 8; ++kk) {
    int k8 = wave * 32 + kk * 4 + kq;
    const bf16* wb = &wlds[(size_t)(k8 * 49 + un) * 8];
    wreg[kk * 3 + 0] = *(const bf16x8*)(wb);
    wreg[kk * 3 + 1] = *(const bf16x8*)(wb + 16 * 8);
    wreg[kk * 3 + 2] = *(const bf16x8*)(wb + 32 * 8);
  }

  float hold0 = h0[(size_t)(0 * 16 + b) * 1024 + jj];
  float hold1 = h0[(size_t)(1 * 16 + b) * 1024 + jj];
  float hold2 = h0[(size_t)(2 * 16 + b) * 1024 + jj];
  float hold3 = h0[(size_t)(3 * 16 + b) * 1024 + jj];
  const float bh0 = bhh[jj], bh1 = bhh[1024 + jj], bh2 = bhh[2048 + jj];

  const bf16* giB = gi + (size_t)b * (512 * 3072) + jj;
  const size_t GSTR = (size_t)16 * 512 * 3072;
  const int aoff0 = ((wave * 32 + kq) * 64 + un) * 8;
  const int hoff0 = ((jj >> 3) * 64 + b) * 8 + (jj & 7);

  // prologue: aff groups 0,1 @ t=0 (buffer 0), gi groups 0,1 @ t=0
  f32x4 affA[8], affB[8];
  u32 gcA0, gcA1, gcA2, gcB0, gcB1, gcB2;
  {
    const bf16* abA = hbuf + aoff0;
    const bf16* abB = hbuf + aoff0 + 128;
#pragma unroll
    for (int kk = 0; kk < 8; ++kk) ld_cc16(abA + kk * 2048, &affA[kk]);
#pragma unroll
    for (int kk = 0; kk < 8; ++kk) ld_cc16(abB + kk * 2048, &affB[kk]);
    const bf16* pA = giB;
    const bf16* pB = giB + GSTR;
    ld_u16(pA, &gcA0); ld_u16(pA + 1024, &gcA1); ld_u16(pA + 2048, &gcA2);
    ld_u16(pB, &gcB0); ld_u16(pB + 1024, &gcB1); ld_u16(pB + 2048, &gcB2);
  }
  WAITV(0);

  int bad = 0;
  for (int t = 0; t < 512; ++t) {
    PHASE2(0, hold0, hold1)
    PHASE2(1, hold2, hold3)
  }
}

__global__ void k_fail(float* out, float v) {
  if (threadIdx.x == 0 && blockIdx.x == 0) out[0] = v;
}

extern "C" void kernel_launch(void* const* d_in, const int* in_sizes, int n_in,
                              void* d_out, int out_size, void* d_ws, size_t ws_size,
                              hipStream_t stream) {
  const float* x   = (const float*)d_in[0];
  const float* h0  = (const float*)d_in[1];
  const float* Wih = (const float*)d_in[2];
  const float* Whh = (const float*)d_in[3];
  const float* bih = (const float*)d_in[4];
  const float* bhh = (const float*)d_in[5];
  float* out = (float*)d_out;

  const size_t GI_BYTES  = (size_t)32768 * 3072 * 2;  // 201,326,592
  const size_t HB_BYTES  = (size_t)2 * 65536 * 2;     // 262,144
  const size_t BAR_BYTES = 4096 * 4;                  // 16,384
  if (ws_size < GI_BYTES + HB_BYTES + BAR_BYTES) {
    k_fail<<<1, 64, 0, stream>>>(out, (float)ws_size);
    return;
  }
  char* ws = (char*)d_ws;
  bf16* gi = (bf16*)ws;
  bf16* hbuf = (bf16*)(ws + GI_BYTES);
  u32* flags = (u32*)(ws + GI_BYTES + HB_BYTES);

  k_init<<<256, 256, 0, stream>>>(h0, hbuf, flags);
  k_gemm<<<6144, 256, 0, stream>>>(x, Wih, bih, gi);
  k_rnn<<<64, 256, 0, stream>>>(h0, Whh, bhh, gi, hbuf, out, flags);
}

// Round 16
// 2889.785 us; speedup vs baseline: 2.5386x; 1.0275x over previous
//
#include <hip/hip_runtime.h>
#include <hip/hip_bf16.h>

// GRU: B=64, S=512, I=1024, H=1024, fp32 in/out, final h only.
// Round 16 = round-13 (best green, deterministic) with ONE change: the flag
// preload is issued at PHASE START (after the aff gate) instead of at the
// previous phase's refill slot. The sample now lands ~1.5 phases after the
// producer's signal (visibility ~400cy) -> preload check hits instead of
// falling into the full-RTT fallback poll. Queue math unchanged: gate
// vmcnt(4) drains exactly aff8 (queue=[aff8,gi3,hstore1]); preload joins
// after the gate and is drained by the per-wave vmcnt(0) before sync#1.

#define B_ 64
#define S_ 512
#define H_ 1024

typedef __bf16 bf16;
typedef __bf16 bf16x8 __attribute__((ext_vector_type(8)));
typedef float  f32x4  __attribute__((ext_vector_type(4)));
typedef unsigned int u32;

// ---- asm helpers (verbatim rounds 2/6/8/12/13) -----------------------------
__device__ __forceinline__ void ld_cc16(const bf16* p, f32x4* dst) {
  asm volatile("global_load_dwordx4 %0, %1, off sc0 sc1" : "=v"(*dst) : "v"(p));
}
__device__ __forceinline__ void ld_u16(const bf16* p, u32* dst) {
  asm volatile("global_load_ushort %0, %1, off" : "=v"(*dst) : "v"(p));
}
__device__ __forceinline__ void st_cc16(bf16* p, u32 bits) {
  asm volatile("global_store_short %0, %1, off sc0 sc1" :: "v"(p), "v"(bits) : "memory");
}

// ---------------- init: zero flags, pack h0 into hbuf[0] --------------------
__global__ void k_init(const float* __restrict__ h0, bf16* __restrict__ hbuf,
                       u32* __restrict__ flags) {
  int t = blockIdx.x * 256 + threadIdx.x;
  if (t < 4096) flags[t] = 0u;
  if (t < B_ * H_) {
    int b = t >> 10, j = t & 1023;
    hbuf[((size_t)((j >> 3) * 64 + b)) * 8 + (j & 7)] = (bf16)h0[t];
  }
}

// ---------------- gi GEMM: [32768,1024] x [1024,3072] -> bf16 ---------------
__global__ __launch_bounds__(256) void k_gemm(const float* __restrict__ X,
                                              const float* __restrict__ W,
                                              const float* __restrict__ bias,
                                              bf16* __restrict__ gi) {
  __shared__ bf16 As[128 * 40];
  __shared__ bf16 Bs[128 * 40];
  const int tid = threadIdx.x;
  const int bidn = blockIdx.x % 24, bidm = blockIdx.x / 24;
  const int row = tid >> 1, half = tid & 1;
  const float* ax = X + (size_t)(bidm * 128 + row) * 1024 + half * 16;
  const float* bw = W + (size_t)(bidn * 128 + row) * 1024 + half * 16;
  const int lane = tid & 63, wave = tid >> 6;
  const int wm = wave >> 1, wn = wave & 1;

  f32x4 acc[4][4];
#pragma unroll
  for (int i = 0; i < 4; ++i)
#pragma unroll
    for (int j = 0; j < 4; ++j) acc[i][j] = (f32x4){0.f, 0.f, 0.f, 0.f};

  for (int ks = 0; ks < 32; ++ks) {
    {
      const float* pa = ax + ks * 32;
      f32x4 a0 = *(const f32x4*)(pa);
      f32x4 a1 = *(const f32x4*)(pa + 4);
      f32x4 a2 = *(const f32x4*)(pa + 8);
      f32x4 a3 = *(const f32x4*)(pa + 12);
      bf16x8 v0, v1;
#pragma unroll
      for (int i = 0; i < 4; ++i) {
        v0[i] = (bf16)a0[i]; v0[4 + i] = (bf16)a1[i];
        v1[i] = (bf16)a2[i]; v1[4 + i] = (bf16)a3[i];
      }
      *(bf16x8*)&As[row * 40 + half * 16]     = v0;
      *(bf16x8*)&As[row * 40 + half * 16 + 8] = v1;

      const float* pb = bw + ks * 32;
      f32x4 b0 = *(const f32x4*)(pb);
      f32x4 b1 = *(const f32x4*)(pb + 4);
      f32x4 b2 = *(const f32x4*)(pb + 8);
      f32x4 b3 = *(const f32x4*)(pb + 12);
#pragma unroll
      for (int i = 0; i < 4; ++i) {
        v0[i] = (bf16)b0[i]; v0[4 + i] = (bf16)b1[i];
        v1[i] = (bf16)b2[i]; v1[4 + i] = (bf16)b3[i];
      }
      *(bf16x8*)&Bs[row * 40 + half * 16]     = v0;
      *(bf16x8*)&Bs[row * 40 + half * 16 + 8] = v1;
    }
    __syncthreads();
    bf16x8 af[4], bfr[4];
#pragma unroll
    for (int mi = 0; mi < 4; ++mi)
      af[mi] = *(const bf16x8*)&As[(wm * 64 + mi * 16 + (lane & 15)) * 40 + (lane >> 4) * 8];
#pragma unroll
    for (int ni = 0; ni < 4; ++ni)
      bfr[ni] = *(const bf16x8*)&Bs[(wn * 64 + ni * 16 + (lane & 15)) * 40 + (lane >> 4) * 8];
#pragma unroll
    for (int mi = 0; mi < 4; ++mi)
#pragma unroll
      for (int ni = 0; ni < 4; ++ni)
        acc[mi][ni] = __builtin_amdgcn_mfma_f32_16x16x32_bf16(af[mi], bfr[ni], acc[mi][ni], 0, 0, 0);
    __syncthreads();
  }

  float bv[4];
#pragma unroll
  for (int ni = 0; ni < 4; ++ni)
    bv[ni] = bias[bidn * 128 + wn * 64 + ni * 16 + (lane & 15)];
#pragma unroll
  for (int mi = 0; mi < 4; ++mi)
#pragma unroll
    for (int ni = 0; ni < 4; ++ni)
#pragma unroll
      for (int r = 0; r < 4; ++r) {
        int grow = bidm * 128 + wm * 64 + mi * 16 + (lane >> 4) * 4 + r;
        int gcol = bidn * 128 + wn * 64 + ni * 16 + (lane & 15);
        gi[(size_t)grow * 3072 + gcol] = (bf16)(acc[mi][ni][r] + bv[ni]);
      }
}

// ---------------- persistent recurrent kernel -------------------------------
// Per phase (grp,t):
//   vmcnt(4) [drains aff8; queue=[aff8,gi3,hstore1]] -> ISSUE flag preload
//   -> 24 MFMA (W in regs) -> plds (stride 48)
//   -> per-wave vmcnt(0) [drains hstore+gi+preload for ALL waves]
//   -> syncthreads(#1) -> signal prev flag -> launder+check preload
//      (fallback poll only on miss) -> s_barrier(#2)
//   -> refill aff(next)+gi(next) -> gates -> h-store -> s_barrier(#3)
__global__ __launch_bounds__(256, 1) void k_rnn(
    const float* __restrict__ h0, const float* __restrict__ Whh,
    const float* __restrict__ bhh, const bf16* __restrict__ gi,
    bf16* __restrict__ hbuf, float* __restrict__ out, u32* __restrict__ flags) {
  __shared__ bf16 wlds[128 * 49 * 8];   // staging; K-loop never reads it
  __shared__ float plds[4 * 16 * 48];   // stride 48 (2-way-free gate read)
  __shared__ float hold[4][256];        // f32 local h per group

  const int tid = threadIdx.x;
  const int Q = blockIdx.x;                // unit block
  const int lane = tid & 63, wave = tid >> 6;
  const int b = tid >> 4, u = tid & 15;

  for (int idx = tid; idx < 48 * 128; idx += 256) {
    int c = idx % 48, k8 = idx / 48;
    int ga = c >> 4, un = c & 15;
    const float* src = Whh + (size_t)(ga * 1024 + Q * 16 + un) * 1024 + k8 * 8;
    bf16x8 v;
#pragma unroll
    for (int e = 0; e < 8; ++e) v[e] = (bf16)src[e];
    *(bf16x8*)&wlds[(size_t)(k8 * 49 + c) * 8] = v;
  }
#pragma unroll
  for (int g = 0; g < 4; ++g)
    hold[g][tid] = h0[(size_t)(g * 16 + b) * 1024 + Q * 16 + u];
  const float bh0 = bhh[Q * 16 + u];
  const float bh1 = bhh[1024 + Q * 16 + u];
  const float bh2 = bhh[2048 + Q * 16 + u];

  const bf16* giB = gi + (size_t)b * (512 * 3072) + Q * 16 + u;
  const size_t GSTR = (size_t)16 * 512 * 3072;
  const int aoff0 = ((wave * 32 + (lane >> 4)) * 64 + (lane & 15)) * 8;
  const int jj = Q * 16 + u;
  const int hoff0 = ((jj >> 3) * 64 + b) * 8 + (jj & 7);

  __syncthreads();

  // W fragments -> registers (proven round 8)
  bf16x8 wreg[24];
#pragma unroll
  for (int kk = 0; kk < 8; ++kk) {
    int k8 = wave * 32 + kk * 4 + (lane >> 4);
    const bf16* wb = &wlds[(size_t)(k8 * 49 + (lane & 15)) * 8];
    wreg[kk * 3 + 0] = *(const bf16x8*)(wb);
    wreg[kk * 3 + 1] = *(const bf16x8*)(wb + 16 * 8);
    wreg[kk * 3 + 2] = *(const bf16x8*)(wb + 32 * 8);
  }

  f32x4 aff[8];
  u32 gc0, gc1, gc2, gn0, gn1, gn2;
  {
    const bf16* ab = hbuf + aoff0;   // buffer 0, grp 0
#pragma unroll
    for (int kk = 0; kk < 8; ++kk) ld_cc16(ab + kk * 2048, &aff[kk]);
    ld_u16(giB, &gc0); ld_u16(giB + 1024, &gc1); ld_u16(giB + 2048, &gc2);
  }

  int bad = 0;
  for (int t = 0; t < 512; ++t) {
    bf16* curb = hbuf + (size_t)(t & 1) * 65536;
    bf16* nxtb = hbuf + (size_t)((t & 1) ^ 1) * 65536;
    for (int grp = 0; grp < 4; ++grp) {
      if (t == 0 && grp == 0) { asm volatile("s_waitcnt vmcnt(0)" ::: "memory"); }
      else                    { asm volatile("s_waitcnt vmcnt(4)" ::: "memory"); }
      __builtin_amdgcn_sched_barrier(0);

      // THE CHANGE vs r13: preload issued HERE (phase start) — samples the
      // flag ~1.5 phases after the producer's signal; drained by the
      // pre-sync vmcnt(0) below, checked after sync#1.
      const bool has_next = !(t == 511 && grp == 3);
      const int ng = (grp + 1) & 3;
      const u32 tn = (u32)((grp < 3) ? t : t + 1);
      u32 fpre = 0xFFFFFFFFu;
      if (has_next && tn && tid < 64) {
        const u32* fp = flags + (ng * 64 + lane) * 16;
        asm volatile("global_load_dword %0, %1, off sc0 sc1" : "=v"(fpre) : "v"(fp));
      }

      f32x4 acc0 = (f32x4){0.f,0.f,0.f,0.f};
      f32x4 acc1 = (f32x4){0.f,0.f,0.f,0.f};
      f32x4 acc2 = (f32x4){0.f,0.f,0.f,0.f};
#pragma unroll
      for (int kk = 0; kk < 8; ++kk) {
        bf16x8 a = __builtin_bit_cast(bf16x8, aff[kk]);
        acc0 = __builtin_amdgcn_mfma_f32_16x16x32_bf16(a, wreg[kk * 3 + 0], acc0, 0, 0, 0);
        acc1 = __builtin_amdgcn_mfma_f32_16x16x32_bf16(a, wreg[kk * 3 + 1], acc1, 0, 0, 0);
        acc2 = __builtin_amdgcn_mfma_f32_16x16x32_bf16(a, wreg[kk * 3 + 2], acc2, 0, 0, 0);
      }
      {
        int prow = wave * 16 + (lane >> 4) * 4;
#pragma unroll
        for (int r = 0; r < 4; ++r) {
          plds[(prow + r) * 48 + (lane & 15)]      = acc0[r];
          plds[(prow + r) * 48 + 16 + (lane & 15)] = acc1[r];
          plds[(prow + r) * 48 + 32 + (lane & 15)] = acc2[r];
        }
      }
      // r12 invariant: per-wave drain BEFORE the barrier (hstore, gi, preload)
      asm volatile("s_waitcnt vmcnt(0)" ::: "memory");
      __builtin_amdgcn_sched_barrier(0);
      __syncthreads();   // #1: all waves drained => deferred signal is sound

      {
        int sg = (grp + 3) & 3;
        int st_ = (grp == 0) ? t - 1 : t;
        if (tid == 0 && st_ >= 0 && st_ < 511)
          __hip_atomic_store(&flags[(sg * 64 + Q) * 16], (u32)(st_ + 1),
                             __ATOMIC_RELAXED, __HIP_MEMORY_SCOPE_AGENT);
        if (has_next && tn && tid < 64) {
          // launder: orders the compare AFTER the pre-sync drain (rule 18)
          asm volatile("" : "+v"(fpre));
          if (!__all(fpre >= tn)) {
            const u32* fp = flags + (ng * 64 + lane) * 16;
            int guard = 0;
            while (1) {
              u32 f = __hip_atomic_load(fp, __ATOMIC_RELAXED,
                                        __HIP_MEMORY_SCOPE_AGENT);
              if (__all(f >= tn)) break;
              if (++guard > (1 << 16)) { bad = 1; break; }
              __builtin_amdgcn_s_sleep(1);
            }
          }
        }
      }
      __builtin_amdgcn_s_barrier();   // #2 raw: release poll result

      if (has_next) {
        const bf16* ab = ((grp < 3) ? curb : nxtb) + aoff0 + ng * 128;
#pragma unroll
        for (int kk = 0; kk < 8; ++kk) ld_cc16(ab + kk * 2048, &aff[kk]);
        int ntp = (grp < 3) ? t : t + 1;
        const bf16* p = giB + (size_t)ng * GSTR + (size_t)ntp * 3072;
        ld_u16(p, &gn0); ld_u16(p + 1024, &gn1); ld_u16(p + 2048, &gn2);
      }

      float ghr = bh0, ghz = bh1, ghn = bh2;
#pragma unroll
      for (int w = 0; w < 4; ++w) {
        ghr += plds[w * 768 + b * 48 + u];
        ghz += plds[w * 768 + b * 48 + 16 + u];
        ghn += plds[w * 768 + b * 48 + 32 + u];
      }
      float gir = __builtin_bit_cast(float, gc0 << 16);
      float giz = __builtin_bit_cast(float, gc1 << 16);
      float gin = __builtin_bit_cast(float, gc2 << 16);
      float rg = 1.f / (1.f + __expf(-(gir + ghr)));
      float zg = 1.f / (1.f + __expf(-(giz + ghz)));
      float e2 = __expf(2.f * (gin + rg * ghn));
      float tng = 1.f - 2.f / (e2 + 1.f);
      float hnew = (1.f - zg) * tng + zg * hold[grp][tid];
      hold[grp][tid] = hnew;
      if (t == 511) {
        if (bad) hnew = 12345.0f;   // stall signature
        out[(size_t)(grp * 16 + b) * 1024 + jj] = hnew;
      } else {
        unsigned short hb = __builtin_bit_cast(unsigned short, (bf16)hnew);
        st_cc16(nxtb + hoff0 + grp * 128, (u32)hb);
      }
      gc0 = gn0; gc1 = gn1; gc2 = gn2;
      __builtin_amdgcn_s_barrier();   // #3 raw: plds reuse fence
    }
  }
}

__global__ void k_fail(float* out, float v) {
  if (threadIdx.x == 0 && blockIdx.x == 0) out[0] = v;
}

extern "C" void kernel_launch(void* const* d_in, const int* in_sizes, int n_in,
                              void* d_out, int out_size, void* d_ws, size_t ws_size,
                              hipStream_t stream) {
  const float* x   = (const float*)d_in[0];
  const float* h0  = (const float*)d_in[1];
  const float* Wih = (const float*)d_in[2];
  const float* Whh = (const float*)d_in[3];
  const float* bih = (const float*)d_in[4];
  const float* bhh = (const float*)d_in[5];
  float* out = (float*)d_out;

  const size_t GI_BYTES  = (size_t)32768 * 3072 * 2;  // 201,326,592
  const size_t HB_BYTES  = (size_t)2 * 65536 * 2;     // 262,144
  const size_t BAR_BYTES = 4096 * 4;                  // 16,384
  if (ws_size < GI_BYTES + HB_BYTES + BAR_BYTES) {
    k_fail<<<1, 64, 0, stream>>>(out, (float)ws_size);
    return;
  }
  char* ws = (char*)d_ws;
  bf16* gi = (bf16*)ws;
  bf16* hbuf = (bf16*)(ws + GI_BYTES);
  u32* flags = (u32*)(ws + GI_BYTES + HB_BYTES);

  k_init<<<256, 256, 0, stream>>>(h0, hbuf, flags);
  k_gemm<<<6144, 256, 0, stream>>>(x, Wih, bih, gi);
  k_rnn<<<64, 256, 0, stream>>>(h0, Whh, bhh, gi, hbuf, out, flags);
}